// Round 1
// baseline (1885.926 us; speedup 1.0000x reference)
//
#include <hip/hip_runtime.h>
#include <cstdint>
#include <cstddef>

namespace {
constexpr int kL = 16;                    // levels
constexpr uint32_t kT = 1u << 19;         // hash table entries per level
constexpr uint32_t kTmask = kT - 1u;
constexpr uint32_t kP1 = 2654435761u;     // spatial hash primes
constexpr uint32_t kP2 = 805459861u;
}

// One thread per (point, level). gtid = p*16 + l.
// Output float2 store at out2[gtid] -> perfectly coalesced 8B/lane.
__global__ __launch_bounds__(256) void hashgrid_fwd(
    const float* __restrict__ x,         // [P,3]
    const float* __restrict__ hashmap,   // [L,T,F] f32
    float2* __restrict__ out2,           // [P, L] of float2
    int total)                           // P*16
{
    const int gtid = blockIdx.x * 256 + threadIdx.x;
    if (gtid >= total) return;
    const int p = gtid >> 4;
    const int l = gtid & 15;

    // res[l] = int(16 * (2^(1/3))^l), computed branchlessly and exactly:
    //   oct = l/3, rem = l%3; res = floor((16<<oct) * c[rem]),
    //   c = {1, 2^(1/3), 2^(2/3)}. rem==0 path is exact integer math;
    //   rem!=0 products are >=0.15 away from integer boundaries.
    const int oct = (l * 11) >> 5;        // == l/3 for l in [0,15]
    const int rem = l - 3 * oct;
    const float base = (float)(16 << oct);
    const float cmul = (rem == 0) ? 1.0f : ((rem == 1) ? 1.2599210499f : 1.5874010520f);
    const int res = (int)(base * cmul);
    const float fres = (float)res;

    // load point (16 lanes share p -> broadcast-friendly)
    const float px = x[p * 3 + 0];
    const float py = x[p * 3 + 1];
    const float pz = x[p * 3 + 2];

    // scale, floor, frac (matches reference fp32 ops exactly)
    const float xs0 = px * fres;
    const float xs1 = py * fres;
    const float xs2 = pz * fres;
    const float fl0 = floorf(xs0);
    const float fl1 = floorf(xs1);
    const float fl2 = floorf(xs2);
    const float fx = xs0 - fl0;
    const float fy = xs1 - fl1;
    const float fz = xs2 - fl2;
    const uint32_t i0 = (uint32_t)(int)fl0;
    const uint32_t i1 = (uint32_t)(int)fl1;
    const uint32_t i2 = (uint32_t)(int)fl2;

    // factored hash: h(c0,c1,c2) = c0 ^ c1*P1 ^ c2*P2 (uint32 wrap)
    const uint32_t h0a = i0;
    const uint32_t h0b = i0 + 1u;
    const uint32_t h1a = i1 * kP1;
    const uint32_t h1b = (i1 + 1u) * kP1;
    const uint32_t h2a = i2 * kP2;
    const uint32_t h2b = (i2 + 1u) * kP2;

    // corner order: (i,j,k), k fastest — matches CORNER_OFFS
    uint32_t idx[8];
    idx[0] = (h0a ^ h1a ^ h2a) & kTmask;
    idx[1] = (h0a ^ h1a ^ h2b) & kTmask;
    idx[2] = (h0a ^ h1b ^ h2a) & kTmask;
    idx[3] = (h0a ^ h1b ^ h2b) & kTmask;
    idx[4] = (h0b ^ h1a ^ h2a) & kTmask;
    idx[5] = (h0b ^ h1a ^ h2b) & kTmask;
    idx[6] = (h0b ^ h1b ^ h2a) & kTmask;
    idx[7] = (h0b ^ h1b ^ h2b) & kTmask;

    // 8 gathers, issued as a cluster before the weight math
    const float2* __restrict__ tbl =
        reinterpret_cast<const float2*>(hashmap) + (size_t)l * (size_t)kT;
    float2 f[8];
#pragma unroll
    for (int c = 0; c < 8; ++c) {
        f[c] = tbl[idx[c]];
    }

    // trilinear weights, left-assoc product like the reference
    const float wx0 = 1.0f - fx, wx1 = fx;
    const float wy0 = 1.0f - fy, wy1 = fy;
    const float wz0 = 1.0f - fz, wz1 = fz;
    float w[8];
    w[0] = wx0 * wy0 * wz0;
    w[1] = wx0 * wy0 * wz1;
    w[2] = wx0 * wy1 * wz0;
    w[3] = wx0 * wy1 * wz1;
    w[4] = wx1 * wy0 * wz0;
    w[5] = wx1 * wy0 * wz1;
    w[6] = wx1 * wy1 * wz0;
    w[7] = wx1 * wy1 * wz1;

    float acc0 = 0.0f, acc1 = 0.0f;
#pragma unroll
    for (int c = 0; c < 8; ++c) {
        acc0 = fmaf(w[c], f[c].x, acc0);
        acc1 = fmaf(w[c], f[c].y, acc1);
    }

    out2[gtid] = make_float2(acc0, acc1);
}

extern "C" void kernel_launch(void* const* d_in, const int* in_sizes, int n_in,
                              void* d_out, int out_size, void* d_ws, size_t ws_size,
                              hipStream_t stream) {
    const float* x = (const float*)d_in[0];        // [P,3] f32
    const float* hashmap = (const float*)d_in[1];  // [L,T,F] f32
    float2* out2 = (float2*)d_out;                 // [P, L*F] f32 viewed as float2

    const int P = in_sizes[0] / 3;
    const int total = P * kL;
    const int block = 256;
    const int grid = (total + block - 1) / block;

    hashgrid_fwd<<<grid, block, 0, stream>>>(x, hashmap, out2, total);
}

// Round 6
// 1481.368 us; speedup vs baseline: 1.2731x; 1.2731x over previous
//
#include <hip/hip_runtime.h>
#include <cstdint>
#include <cstddef>

namespace {
constexpr int kL = 16;                    // levels
constexpr uint32_t kT = 1u << 19;         // hash table entries per level
constexpr uint32_t kTmask = kT - 1u;
constexpr uint32_t kP1 = 2654435761u;     // spatial hash primes
constexpr uint32_t kP2 = 805459861u;
}

// One thread per POINT. Each thread processes all 16 levels (unrolled,
// compile-time resolutions), accumulates 16 float2 in registers, then
// writes its 128B output row contiguously.
//
// Why: the round-1 thread-per-(point,level) mapping put all 16 hash
// tables (64 MB) in every XCD's working set -> L2 thrash, 6.7 GB HBM
// fetch. With a per-block level loop, resident blocks advance through
// levels roughly in lockstep, so the instantaneous working set is
// ~1-3 tables (4-12 MB) -> L2-resident gathers.
__global__ __launch_bounds__(256) void hashgrid_fwd(
    const float* __restrict__ x,         // [P,3]
    const float* __restrict__ hashmap,   // [L,T,F] f32
    float4* __restrict__ out4,           // [P*8] float4 (= [P,32] f32)
    int P)
{
    // RES[l] = int(16 * 2^(l/3)) — matches the reference's resolutions
    constexpr int RES[16] = {16, 20, 25, 32, 40, 50, 64, 80,
                             101, 128, 161, 203, 256, 322, 406, 512};

    const int p = blockIdx.x * 256 + threadIdx.x;
    if (p >= P) return;

    const float px = x[p * 3 + 0];
    const float py = x[p * 3 + 1];
    const float pz = x[p * 3 + 2];

    float acc[32];  // statically indexed (full unroll) -> stays in VGPRs

#pragma unroll
    for (int l = 0; l < kL; ++l) {
        const float fres = (float)RES[l];

        // scale, floor, frac (fp32 ops match the reference exactly)
        const float xs0 = px * fres;
        const float xs1 = py * fres;
        const float xs2 = pz * fres;
        const float fl0 = floorf(xs0);
        const float fl1 = floorf(xs1);
        const float fl2 = floorf(xs2);
        const float fx = xs0 - fl0;
        const float fy = xs1 - fl1;
        const float fz = xs2 - fl2;
        const uint32_t i0 = (uint32_t)(int)fl0;
        const uint32_t i1 = (uint32_t)(int)fl1;
        const uint32_t i2 = (uint32_t)(int)fl2;

        // factored hash: h(c0,c1,c2) = c0 ^ c1*P1 ^ c2*P2 (uint32 wrap)
        const uint32_t h0a = i0;
        const uint32_t h0b = i0 + 1u;
        const uint32_t h1a = i1 * kP1;
        const uint32_t h1b = (i1 + 1u) * kP1;
        const uint32_t h2a = i2 * kP2;
        const uint32_t h2b = (i2 + 1u) * kP2;

        uint32_t idx[8];
        idx[0] = (h0a ^ h1a ^ h2a) & kTmask;
        idx[1] = (h0a ^ h1a ^ h2b) & kTmask;
        idx[2] = (h0a ^ h1b ^ h2a) & kTmask;
        idx[3] = (h0a ^ h1b ^ h2b) & kTmask;
        idx[4] = (h0b ^ h1a ^ h2a) & kTmask;
        idx[5] = (h0b ^ h1a ^ h2b) & kTmask;
        idx[6] = (h0b ^ h1b ^ h2a) & kTmask;
        idx[7] = (h0b ^ h1b ^ h2b) & kTmask;

        const float2* __restrict__ tbl =
            reinterpret_cast<const float2*>(hashmap) + (size_t)l * (size_t)kT;
        float2 f[8];
#pragma unroll
        for (int c = 0; c < 8; ++c) {
            f[c] = tbl[idx[c]];
        }

        // trilinear weights, left-assoc product like the reference
        const float wx0 = 1.0f - fx, wx1 = fx;
        const float wy0 = 1.0f - fy, wy1 = fy;
        const float wz0 = 1.0f - fz, wz1 = fz;
        float w[8];
        w[0] = wx0 * wy0 * wz0;
        w[1] = wx0 * wy0 * wz1;
        w[2] = wx0 * wy1 * wz0;
        w[3] = wx0 * wy1 * wz1;
        w[4] = wx1 * wy0 * wz0;
        w[5] = wx1 * wy0 * wz1;
        w[6] = wx1 * wy1 * wz0;
        w[7] = wx1 * wy1 * wz1;

        float a0 = 0.0f, a1 = 0.0f;
#pragma unroll
        for (int c = 0; c < 8; ++c) {
            a0 = fmaf(w[c], f[c].x, a0);
            a1 = fmaf(w[c], f[c].y, a1);
        }
        acc[2 * l + 0] = a0;
        acc[2 * l + 1] = a1;
    }

    // contiguous 128B store per thread
    float4* __restrict__ dst = out4 + (size_t)p * 8;
#pragma unroll
    for (int j = 0; j < 8; ++j) {
        dst[j] = make_float4(acc[4 * j + 0], acc[4 * j + 1],
                             acc[4 * j + 2], acc[4 * j + 3]);
    }
}

extern "C" void kernel_launch(void* const* d_in, const int* in_sizes, int n_in,
                              void* d_out, int out_size, void* d_ws, size_t ws_size,
                              hipStream_t stream) {
    const float* x = (const float*)d_in[0];        // [P,3] f32
    const float* hashmap = (const float*)d_in[1];  // [L,T,F] f32
    float4* out4 = (float4*)d_out;                 // [P,32] f32 as float4

    const int P = in_sizes[0] / 3;
    const int block = 256;
    const int grid = (P + block - 1) / block;

    hashgrid_fwd<<<grid, block, 0, stream>>>(x, hashmap, out4, P);
}

// Round 7
// 1305.386 us; speedup vs baseline: 1.4447x; 1.1348x over previous
//
#include <hip/hip_runtime.h>
#include <cstdint>
#include <cstddef>

namespace {
constexpr int kL = 16;                    // levels
constexpr uint32_t kT = 1u << 19;         // hash table entries per level
constexpr uint32_t kTmask = kT - 1u;
constexpr uint32_t kP1 = 2654435761u;     // spatial hash primes
constexpr uint32_t kP2 = 805459861u;
}

// ---------------------------------------------------------------------------
// Level-major pass: one kernel per level. GPU-wide working set = ONE 4MB
// table -> L2-resident on every XCD by construction (round-6 showed the
// statistical "lockstep" of a per-thread level loop does NOT hold: FETCH
// was 4.5GB vs 0.5GB compulsory). Results go to ws[l][p] (coalesced
// float2); a final pass transposes to out[p][32].
// ---------------------------------------------------------------------------
template <int RES, int LVL>
__global__ __launch_bounds__(256) void hashgrid_level(
    const float* __restrict__ x,         // [P,3]
    const float* __restrict__ hashmap,   // [L,T,F] f32
    float2* __restrict__ ws2,            // [kL][P] float2
    int P)
{
    const int p = blockIdx.x * 256 + threadIdx.x;
    if (p >= P) return;

    const float fres = (float)RES;
    const float px = x[p * 3 + 0];
    const float py = x[p * 3 + 1];
    const float pz = x[p * 3 + 2];

    // scale, floor, frac (fp32 ops match the reference exactly)
    const float xs0 = px * fres;
    const float xs1 = py * fres;
    const float xs2 = pz * fres;
    const float fl0 = floorf(xs0);
    const float fl1 = floorf(xs1);
    const float fl2 = floorf(xs2);
    const float fx = xs0 - fl0;
    const float fy = xs1 - fl1;
    const float fz = xs2 - fl2;
    const uint32_t i0 = (uint32_t)(int)fl0;
    const uint32_t i1 = (uint32_t)(int)fl1;
    const uint32_t i2 = (uint32_t)(int)fl2;

    // factored hash: h(c0,c1,c2) = c0 ^ c1*P1 ^ c2*P2 (uint32 wrap)
    const uint32_t h0a = i0;
    const uint32_t h0b = i0 + 1u;
    const uint32_t h1a = i1 * kP1;
    const uint32_t h1b = (i1 + 1u) * kP1;
    const uint32_t h2a = i2 * kP2;
    const uint32_t h2b = (i2 + 1u) * kP2;

    uint32_t idx[8];
    idx[0] = (h0a ^ h1a ^ h2a) & kTmask;
    idx[1] = (h0a ^ h1a ^ h2b) & kTmask;
    idx[2] = (h0a ^ h1b ^ h2a) & kTmask;
    idx[3] = (h0a ^ h1b ^ h2b) & kTmask;
    idx[4] = (h0b ^ h1a ^ h2a) & kTmask;
    idx[5] = (h0b ^ h1a ^ h2b) & kTmask;
    idx[6] = (h0b ^ h1b ^ h2a) & kTmask;
    idx[7] = (h0b ^ h1b ^ h2b) & kTmask;

    const float2* __restrict__ tbl =
        reinterpret_cast<const float2*>(hashmap) + (size_t)LVL * (size_t)kT;
    float2 f[8];
#pragma unroll
    for (int c = 0; c < 8; ++c) {
        f[c] = tbl[idx[c]];
    }

    // trilinear weights, left-assoc product like the reference
    const float wx0 = 1.0f - fx, wx1 = fx;
    const float wy0 = 1.0f - fy, wy1 = fy;
    const float wz0 = 1.0f - fz, wz1 = fz;
    float w[8];
    w[0] = wx0 * wy0 * wz0;
    w[1] = wx0 * wy0 * wz1;
    w[2] = wx0 * wy1 * wz0;
    w[3] = wx0 * wy1 * wz1;
    w[4] = wx1 * wy0 * wz0;
    w[5] = wx1 * wy0 * wz1;
    w[6] = wx1 * wy1 * wz0;
    w[7] = wx1 * wy1 * wz1;

    float a0 = 0.0f, a1 = 0.0f;
#pragma unroll
    for (int c = 0; c < 8; ++c) {
        a0 = fmaf(w[c], f[c].x, a0);
        a1 = fmaf(w[c], f[c].y, a1);
    }

    // coalesced float2 store (wave = 512B contiguous)
    ws2[(size_t)LVL * (size_t)P + (size_t)p] = make_float2(a0, a1);
}

// ws[l][p] float2  ->  out[p][32] f32. All reads/writes fully coalesced.
__global__ __launch_bounds__(256) void hashgrid_transpose(
    const float2* __restrict__ ws2,      // [kL][P]
    float4* __restrict__ out4,           // [P*8]
    int P)
{
    const int p = blockIdx.x * 256 + threadIdx.x;
    if (p >= P) return;
    float2 v[kL];
#pragma unroll
    for (int l = 0; l < kL; ++l) {
        v[l] = ws2[(size_t)l * (size_t)P + (size_t)p];
    }
    float4* __restrict__ dst = out4 + (size_t)p * 8;
#pragma unroll
    for (int j = 0; j < 8; ++j) {
        dst[j] = make_float4(v[2 * j].x, v[2 * j].y,
                             v[2 * j + 1].x, v[2 * j + 1].y);
    }
}

// ---------------------------------------------------------------------------
// Fallback (round-6 monolithic): used only if ws_size can't hold [L][P]f2.
// ---------------------------------------------------------------------------
__global__ __launch_bounds__(256) void hashgrid_fwd_mono(
    const float* __restrict__ x,
    const float* __restrict__ hashmap,
    float4* __restrict__ out4,
    int P)
{
    constexpr int RES[16] = {16, 20, 25, 32, 40, 50, 64, 80,
                             101, 128, 161, 203, 256, 322, 406, 512};
    const int p = blockIdx.x * 256 + threadIdx.x;
    if (p >= P) return;
    const float px = x[p * 3 + 0];
    const float py = x[p * 3 + 1];
    const float pz = x[p * 3 + 2];
    float acc[32];
#pragma unroll
    for (int l = 0; l < kL; ++l) {
        const float fres = (float)RES[l];
        const float xs0 = px * fres, xs1 = py * fres, xs2 = pz * fres;
        const float fl0 = floorf(xs0), fl1 = floorf(xs1), fl2 = floorf(xs2);
        const float fx = xs0 - fl0, fy = xs1 - fl1, fz = xs2 - fl2;
        const uint32_t i0 = (uint32_t)(int)fl0;
        const uint32_t i1 = (uint32_t)(int)fl1;
        const uint32_t i2 = (uint32_t)(int)fl2;
        const uint32_t h0a = i0, h0b = i0 + 1u;
        const uint32_t h1a = i1 * kP1, h1b = (i1 + 1u) * kP1;
        const uint32_t h2a = i2 * kP2, h2b = (i2 + 1u) * kP2;
        uint32_t idx[8];
        idx[0] = (h0a ^ h1a ^ h2a) & kTmask;
        idx[1] = (h0a ^ h1a ^ h2b) & kTmask;
        idx[2] = (h0a ^ h1b ^ h2a) & kTmask;
        idx[3] = (h0a ^ h1b ^ h2b) & kTmask;
        idx[4] = (h0b ^ h1a ^ h2a) & kTmask;
        idx[5] = (h0b ^ h1a ^ h2b) & kTmask;
        idx[6] = (h0b ^ h1b ^ h2a) & kTmask;
        idx[7] = (h0b ^ h1b ^ h2b) & kTmask;
        const float2* __restrict__ tbl =
            reinterpret_cast<const float2*>(hashmap) + (size_t)l * (size_t)kT;
        float2 f[8];
#pragma unroll
        for (int c = 0; c < 8; ++c) f[c] = tbl[idx[c]];
        const float wx0 = 1.0f - fx, wx1 = fx;
        const float wy0 = 1.0f - fy, wy1 = fy;
        const float wz0 = 1.0f - fz, wz1 = fz;
        float w[8];
        w[0] = wx0 * wy0 * wz0;
        w[1] = wx0 * wy0 * wz1;
        w[2] = wx0 * wy1 * wz0;
        w[3] = wx0 * wy1 * wz1;
        w[4] = wx1 * wy0 * wz0;
        w[5] = wx1 * wy0 * wz1;
        w[6] = wx1 * wy1 * wz0;
        w[7] = wx1 * wy1 * wz1;
        float a0 = 0.0f, a1 = 0.0f;
#pragma unroll
        for (int c = 0; c < 8; ++c) {
            a0 = fmaf(w[c], f[c].x, a0);
            a1 = fmaf(w[c], f[c].y, a1);
        }
        acc[2 * l + 0] = a0;
        acc[2 * l + 1] = a1;
    }
    float4* __restrict__ dst = out4 + (size_t)p * 8;
#pragma unroll
    for (int j = 0; j < 8; ++j) {
        dst[j] = make_float4(acc[4 * j + 0], acc[4 * j + 1],
                             acc[4 * j + 2], acc[4 * j + 3]);
    }
}

extern "C" void kernel_launch(void* const* d_in, const int* in_sizes, int n_in,
                              void* d_out, int out_size, void* d_ws, size_t ws_size,
                              hipStream_t stream) {
    const float* x = (const float*)d_in[0];        // [P,3] f32
    const float* hashmap = (const float*)d_in[1];  // [L,T,F] f32
    float4* out4 = (float4*)d_out;                 // [P,32] f32 as float4

    const int P = in_sizes[0] / 3;
    const int block = 256;
    const int grid = (P + block - 1) / block;

    const size_t ws_needed = (size_t)kL * (size_t)P * sizeof(float2);
    if (ws_size < ws_needed) {
        // workspace too small for the level-major path
        hashgrid_fwd_mono<<<grid, block, 0, stream>>>(x, hashmap, out4, P);
        return;
    }

    float2* ws2 = (float2*)d_ws;

#define LAUNCH_LEVEL(R, L) \
    hashgrid_level<R, L><<<grid, block, 0, stream>>>(x, hashmap, ws2, P)

    LAUNCH_LEVEL(16, 0);
    LAUNCH_LEVEL(20, 1);
    LAUNCH_LEVEL(25, 2);
    LAUNCH_LEVEL(32, 3);
    LAUNCH_LEVEL(40, 4);
    LAUNCH_LEVEL(50, 5);
    LAUNCH_LEVEL(64, 6);
    LAUNCH_LEVEL(80, 7);
    LAUNCH_LEVEL(101, 8);
    LAUNCH_LEVEL(128, 9);
    LAUNCH_LEVEL(161, 10);
    LAUNCH_LEVEL(203, 11);
    LAUNCH_LEVEL(256, 12);
    LAUNCH_LEVEL(322, 13);
    LAUNCH_LEVEL(406, 14);
    LAUNCH_LEVEL(512, 15);
#undef LAUNCH_LEVEL

    hashgrid_transpose<<<grid, block, 0, stream>>>(ws2, out4, P);
}

// Round 8
// 1221.367 us; speedup vs baseline: 1.5441x; 1.0688x over previous
//
#include <hip/hip_runtime.h>
#include <cstdint>
#include <cstddef>

namespace {
constexpr int kL = 16;                    // levels
constexpr uint32_t kT = 1u << 19;         // hash table entries per level
constexpr uint32_t kTmask = kT - 1u;
constexpr uint32_t kP1 = 2654435761u;     // spatial hash primes
constexpr uint32_t kP2 = 805459861u;
}

// Per-point prep: everything except the gathers (indices + weights).
struct Prep {
    uint32_t idx[8];
    float w[8];
};

__device__ __forceinline__ void prep_point(float px, float py, float pz,
                                           float fres, Prep& pr) {
    // scale, floor, frac (fp32 ops match the reference exactly)
    const float xs0 = px * fres;
    const float xs1 = py * fres;
    const float xs2 = pz * fres;
    const float fl0 = floorf(xs0);
    const float fl1 = floorf(xs1);
    const float fl2 = floorf(xs2);
    const float fx = xs0 - fl0;
    const float fy = xs1 - fl1;
    const float fz = xs2 - fl2;
    const uint32_t i0 = (uint32_t)(int)fl0;
    const uint32_t i1 = (uint32_t)(int)fl1;
    const uint32_t i2 = (uint32_t)(int)fl2;

    // factored hash: h(c0,c1,c2) = c0 ^ c1*P1 ^ c2*P2 (uint32 wrap)
    const uint32_t h0a = i0;
    const uint32_t h0b = i0 + 1u;
    const uint32_t h1a = i1 * kP1;
    const uint32_t h1b = (i1 + 1u) * kP1;
    const uint32_t h2a = i2 * kP2;
    const uint32_t h2b = (i2 + 1u) * kP2;

    pr.idx[0] = (h0a ^ h1a ^ h2a) & kTmask;
    pr.idx[1] = (h0a ^ h1a ^ h2b) & kTmask;
    pr.idx[2] = (h0a ^ h1b ^ h2a) & kTmask;
    pr.idx[3] = (h0a ^ h1b ^ h2b) & kTmask;
    pr.idx[4] = (h0b ^ h1a ^ h2a) & kTmask;
    pr.idx[5] = (h0b ^ h1a ^ h2b) & kTmask;
    pr.idx[6] = (h0b ^ h1b ^ h2a) & kTmask;
    pr.idx[7] = (h0b ^ h1b ^ h2b) & kTmask;

    const float wx0 = 1.0f - fx, wx1 = fx;
    const float wy0 = 1.0f - fy, wy1 = fy;
    const float wz0 = 1.0f - fz, wz1 = fz;
    pr.w[0] = wx0 * wy0 * wz0;
    pr.w[1] = wx0 * wy0 * wz1;
    pr.w[2] = wx0 * wy1 * wz0;
    pr.w[3] = wx0 * wy1 * wz1;
    pr.w[4] = wx1 * wy0 * wz0;
    pr.w[5] = wx1 * wy0 * wz1;
    pr.w[6] = wx1 * wy1 * wz0;
    pr.w[7] = wx1 * wy1 * wz1;
}

// ---------------------------------------------------------------------------
// Level-major pass, 2 points per thread: GPU-wide working set = ONE 4MB
// table -> L2-resident per XCD by construction. 16 outstanding gathers
// per thread (vs 8) to cover L2 latency. ws store = one float4
// (two adjacent points' float2), fully coalesced.
// ---------------------------------------------------------------------------
template <int RES, int LVL>
__global__ __launch_bounds__(256) void hashgrid_level2(
    const float* __restrict__ x,         // [P,3]
    const float* __restrict__ hashmap,   // [L,T,F] f32
    float2* __restrict__ ws2,            // [kL][P] float2
    int P)
{
    const int t = blockIdx.x * 256 + threadIdx.x;
    const int p0 = 2 * t;
    if (p0 >= P) return;

    const float fres = (float)RES;
    const float* __restrict__ xp = x + (size_t)p0 * 3;
    const float ax = xp[0], ay = xp[1], az = xp[2];
    const float bx = xp[3], by = xp[4], bz = xp[5];

    Prep A, B;
    prep_point(ax, ay, az, fres, A);
    prep_point(bx, by, bz, fres, B);

    const float2* __restrict__ tbl =
        reinterpret_cast<const float2*>(hashmap) + (size_t)LVL * (size_t)kT;

    // 16 gathers issued as one cluster
    float2 fa[8], fb[8];
#pragma unroll
    for (int c = 0; c < 8; ++c) fa[c] = tbl[A.idx[c]];
#pragma unroll
    for (int c = 0; c < 8; ++c) fb[c] = tbl[B.idx[c]];

    float a0 = 0.0f, a1 = 0.0f, b0 = 0.0f, b1 = 0.0f;
#pragma unroll
    for (int c = 0; c < 8; ++c) {
        a0 = fmaf(A.w[c], fa[c].x, a0);
        a1 = fmaf(A.w[c], fa[c].y, a1);
        b0 = fmaf(B.w[c], fb[c].x, b0);
        b1 = fmaf(B.w[c], fb[c].y, b1);
    }

    float2* dst = ws2 + (size_t)LVL * (size_t)P + (size_t)p0;
    if (p0 + 1 < P) {
        // p0 even -> 16B aligned float4 store
        *reinterpret_cast<float4*>(dst) = make_float4(a0, a1, b0, b1);
    } else {
        *dst = make_float2(a0, a1);
    }
}

// ---------------------------------------------------------------------------
// ws[l][p] float2 -> out[p][32] f32, LDS-staged so BOTH sides are
// perfectly lane-coalesced (round-7 version had stride-128B stores ->
// 3.8x HBM write amplification, 300us).
// LDS [256][17] float2: pad 17 breaks the 32-way bank conflict on the
// write phase (stride 136B -> 2-way aliasing, free per m136).
// ---------------------------------------------------------------------------
__global__ __launch_bounds__(256) void hashgrid_transpose(
    const float2* __restrict__ ws2,      // [kL][P]
    float4* __restrict__ out4,           // [P*8]
    int P)
{
    __shared__ float2 lds[256 * 17];
    const int tid = threadIdx.x;
    const int base = blockIdx.x * 256;

    // read phase: for each level, 256 consecutive float2 (2KB) -> LDS
#pragma unroll
    for (int l = 0; l < kL; ++l) {
        const int p = base + tid;
        float2 v = (p < P) ? ws2[(size_t)l * (size_t)P + (size_t)p]
                           : make_float2(0.0f, 0.0f);
        lds[tid * 17 + l] = v;
    }
    __syncthreads();

    // write phase: 2048 float4 for this block's 256 points,
    // consecutive lanes -> consecutive 16B -> perfect coalescing.
    const int nvec = min(P - base, 256) * 8;
#pragma unroll
    for (int j = 0; j < 8; ++j) {
        const int tvec = j * 256 + tid;          // 0..2047
        if (tvec < nvec) {
            const int pl = tvec >> 3;            // local point
            const int m = tvec & 7;              // which float4 of the row
            const float2 a = lds[pl * 17 + 2 * m];
            const float2 b = lds[pl * 17 + 2 * m + 1];
            out4[(size_t)base * 8 + (size_t)tvec] = make_float4(a.x, a.y, b.x, b.y);
        }
    }
}

// ---------------------------------------------------------------------------
// Fallback (round-6 monolithic): used only if ws_size can't hold [L][P]f2.
// ---------------------------------------------------------------------------
__global__ __launch_bounds__(256) void hashgrid_fwd_mono(
    const float* __restrict__ x,
    const float* __restrict__ hashmap,
    float4* __restrict__ out4,
    int P)
{
    constexpr int RES[16] = {16, 20, 25, 32, 40, 50, 64, 80,
                             101, 128, 161, 203, 256, 322, 406, 512};
    const int p = blockIdx.x * 256 + threadIdx.x;
    if (p >= P) return;
    const float px = x[p * 3 + 0];
    const float py = x[p * 3 + 1];
    const float pz = x[p * 3 + 2];
    float acc[32];
#pragma unroll
    for (int l = 0; l < kL; ++l) {
        Prep pr;
        prep_point(px, py, pz, (float)RES[l], pr);
        const float2* __restrict__ tbl =
            reinterpret_cast<const float2*>(hashmap) + (size_t)l * (size_t)kT;
        float2 f[8];
#pragma unroll
        for (int c = 0; c < 8; ++c) f[c] = tbl[pr.idx[c]];
        float a0 = 0.0f, a1 = 0.0f;
#pragma unroll
        for (int c = 0; c < 8; ++c) {
            a0 = fmaf(pr.w[c], f[c].x, a0);
            a1 = fmaf(pr.w[c], f[c].y, a1);
        }
        acc[2 * l + 0] = a0;
        acc[2 * l + 1] = a1;
    }
    float4* __restrict__ dst = out4 + (size_t)p * 8;
#pragma unroll
    for (int j = 0; j < 8; ++j) {
        dst[j] = make_float4(acc[4 * j + 0], acc[4 * j + 1],
                             acc[4 * j + 2], acc[4 * j + 3]);
    }
}

extern "C" void kernel_launch(void* const* d_in, const int* in_sizes, int n_in,
                              void* d_out, int out_size, void* d_ws, size_t ws_size,
                              hipStream_t stream) {
    const float* x = (const float*)d_in[0];        // [P,3] f32
    const float* hashmap = (const float*)d_in[1];  // [L,T,F] f32
    float4* out4 = (float4*)d_out;                 // [P,32] f32 as float4

    const int P = in_sizes[0] / 3;
    const int block = 256;
    const int grid_p = (P + block - 1) / block;            // per-point grids
    const int grid_h = ((P + 1) / 2 + block - 1) / block;  // 2 points/thread

    const size_t ws_needed = (size_t)kL * (size_t)P * sizeof(float2);
    if (ws_size < ws_needed) {
        hashgrid_fwd_mono<<<grid_p, block, 0, stream>>>(x, hashmap, out4, P);
        return;
    }

    float2* ws2 = (float2*)d_ws;

#define LAUNCH_LEVEL(R, L) \
    hashgrid_level2<R, L><<<grid_h, block, 0, stream>>>(x, hashmap, ws2, P)

    LAUNCH_LEVEL(16, 0);
    LAUNCH_LEVEL(20, 1);
    LAUNCH_LEVEL(25, 2);
    LAUNCH_LEVEL(32, 3);
    LAUNCH_LEVEL(40, 4);
    LAUNCH_LEVEL(50, 5);
    LAUNCH_LEVEL(64, 6);
    LAUNCH_LEVEL(80, 7);
    LAUNCH_LEVEL(101, 8);
    LAUNCH_LEVEL(128, 9);
    LAUNCH_LEVEL(161, 10);
    LAUNCH_LEVEL(203, 11);
    LAUNCH_LEVEL(256, 12);
    LAUNCH_LEVEL(322, 13);
    LAUNCH_LEVEL(406, 14);
    LAUNCH_LEVEL(512, 15);
#undef LAUNCH_LEVEL

    hashgrid_transpose<<<grid_p, block, 0, stream>>>(ws2, out4, P);
}